// Round 18
// baseline (156.492 us; speedup 1.0000x reference)
//
#include <hip/hip_runtime.h>

#define TT 256
#define BB 8192
#define DD 16
#define HH 8

#define INV_2PI 0.15915494309189535f
#define LOG2E   1.4426950408889634f
#define NEG2LOG2E (-2.0f * LOG2E)

__device__ __forceinline__ float fast_rcp(float v) { return __builtin_amdgcn_rcpf(v); }

// part-exchange: lane ^ 8 within a 16-lane row == DPP row_ror:8 (direction-symmetric). No DS.
#define DPPX8(v) __int_as_float(__builtin_amdgcn_mov_dpp(__float_as_int(v), 0x128, 0xF, 0xF, true))
// quad broadcast via DPP quad_perm
#define QBCAST(x, g) __int_as_float(__builtin_amdgcn_mov_dpp(__float_as_int(x), (g)*0x55, 0xF, 0xF, true))

// matvec x-part for one row (flat 16-float weight array W, bias seed BS) -> AB
#define MV_X(W, BS, AB) do { \
    float A_ = fmaf(W[0], px0.x, BS); \
    A_ = fmaf(W[1],  px0.y, A_); A_ = fmaf(W[2],  px0.z, A_); \
    A_ = fmaf(W[3],  px0.w, A_); A_ = fmaf(W[4],  px1.x, A_); \
    A_ = fmaf(W[5],  px1.y, A_); A_ = fmaf(W[6],  px1.z, A_); \
    A_ = fmaf(W[7],  px1.w, A_); \
    float B_ = W[8] * px2.x; \
    B_ = fmaf(W[9],  px2.y, B_); B_ = fmaf(W[10], px2.z, B_); \
    B_ = fmaf(W[11], px2.w, B_); B_ = fmaf(W[12], px3.x, B_); \
    B_ = fmaf(W[13], px3.y, B_); B_ = fmaf(W[14], px3.z, B_); \
    B_ = fmaf(W[15], px3.w, B_); \
    AB = A_ + B_; } while (0)

// matvec h-part: own-part h (local regs) + remote-part h (DPP'd), weights pre-split at setup
#define MV_H(P, AB, A) do { \
    float C_ = P##ho0 * h0; \
    C_ = fmaf(P##ho1, h1, C_); C_ = fmaf(P##ho2, h2, C_); C_ = fmaf(P##ho3, h3, C_); \
    float D_ = P##ht0 * rh0; \
    D_ = fmaf(P##ht1, rh1, D_); D_ = fmaf(P##ht2, rh2, D_); D_ = fmaf(P##ht3, rh3, D_); \
    A = (AB + C_) + D_; } while (0)

// one transfer-recursion step at wire i
#define RSTEP(i, inext) do { \
    float n0_ = g2_##i * fmaf(bzv##i, fz, -(syv##i * fy)); \
    float nx_ = hn_##i * fmaf(bxv##i, f0, fx); \
    float ny_ = hn_##i * fmaf(syv##i, fz, bzv##i * fy); \
    float nz_ = g2_##i * fmaf(bxv##i, fx, f0); \
    f0 = n0_; fx = nx_; fy = ny_; fz = nz_; \
    E##i = fmaf(bxv##inext, fx, f0); } while (0)

__global__ __launch_bounds__(256, 1)
void qlstm_fused_kernel(const float* __restrict__ inp,
                        const float* __restrict__ Wf, const float* __restrict__ bfv,
                        const float* __restrict__ Wi, const float* __restrict__ biv,
                        const float* __restrict__ Wu, const float* __restrict__ buv,
                        const float* __restrict__ Wo, const float* __restrict__ bov,
                        const float* __restrict__ pf, const float* __restrict__ pi,
                        const float* __restrict__ pu, const float* __restrict__ po,
                        float* __restrict__ out)
{
    const int tid  = blockIdx.x * blockDim.x + threadIdx.x;
    const int gate = tid & 3;          // lane bits 0-1: gate (quad)
    const int samp = (tid >> 2) & 1;   // lane bit 2: which of the row's 2 samples
    const int part = (tid >> 3) & 1;   // lane bit 3: part; xor-8 = row_ror:8
    const int b    = ((tid >> 4) << 1) | samp;   // sample index

    const float* Wg = (gate == 0) ? Wf  : (gate == 1) ? Wi  : (gate == 2) ? Wu  : Wo;
    const float* bg = (gate == 0) ? bfv : (gate == 1) ? biv : (gate == 2) ? buv : bov;
    const float* pp = (gate == 0) ? pf  : (gate == 1) ? pi  : (gate == 2) ? pu  : po;

    // ---- own 4 weight rows: x-part flat; h-part split own/remote (named scalars) ----
    const int r0 = 4 * part;
    float w0[16], w1[16], w2[16], w3[16];
    {
        const float* p0 = Wg + (r0 + 0) * 24;
        const float* p1 = Wg + (r0 + 1) * 24;
        const float* p2 = Wg + (r0 + 2) * 24;
        const float* p3 = Wg + (r0 + 3) * 24;
        #pragma unroll
        for (int k = 0; k < 4; ++k) {
            float4 v0 = *(const float4*)(p0 + 4 * k);
            float4 v1 = *(const float4*)(p1 + 4 * k);
            float4 v2 = *(const float4*)(p2 + 4 * k);
            float4 v3 = *(const float4*)(p3 + 4 * k);
            w0[4*k+0] = v0.x * INV_2PI; w0[4*k+1] = v0.y * INV_2PI;
            w0[4*k+2] = v0.z * INV_2PI; w0[4*k+3] = v0.w * INV_2PI;
            w1[4*k+0] = v1.x * INV_2PI; w1[4*k+1] = v1.y * INV_2PI;
            w1[4*k+2] = v1.z * INV_2PI; w1[4*k+3] = v1.w * INV_2PI;
            w2[4*k+0] = v2.x * INV_2PI; w2[4*k+1] = v2.y * INV_2PI;
            w2[4*k+2] = v2.z * INV_2PI; w2[4*k+3] = v2.w * INV_2PI;
            w3[4*k+0] = v3.x * INV_2PI; w3[4*k+1] = v3.y * INV_2PI;
            w3[4*k+2] = v3.z * INV_2PI; w3[4*k+3] = v3.w * INV_2PI;
        }
    }
    const int ho = 16 + 4 * part, ht = 16 + 4 * (1 - part);
    const float* q0 = Wg + (r0 + 0) * 24;
    const float* q1 = Wg + (r0 + 1) * 24;
    const float* q2 = Wg + (r0 + 2) * 24;
    const float* q3 = Wg + (r0 + 3) * 24;
    const float w0ho0 = q0[ho+0]*INV_2PI, w0ho1 = q0[ho+1]*INV_2PI, w0ho2 = q0[ho+2]*INV_2PI, w0ho3 = q0[ho+3]*INV_2PI;
    const float w0ht0 = q0[ht+0]*INV_2PI, w0ht1 = q0[ht+1]*INV_2PI, w0ht2 = q0[ht+2]*INV_2PI, w0ht3 = q0[ht+3]*INV_2PI;
    const float w1ho0 = q1[ho+0]*INV_2PI, w1ho1 = q1[ho+1]*INV_2PI, w1ho2 = q1[ho+2]*INV_2PI, w1ho3 = q1[ho+3]*INV_2PI;
    const float w1ht0 = q1[ht+0]*INV_2PI, w1ht1 = q1[ht+1]*INV_2PI, w1ht2 = q1[ht+2]*INV_2PI, w1ht3 = q1[ht+3]*INV_2PI;
    const float w2ho0 = q2[ho+0]*INV_2PI, w2ho1 = q2[ho+1]*INV_2PI, w2ho2 = q2[ho+2]*INV_2PI, w2ho3 = q2[ho+3]*INV_2PI;
    const float w2ht0 = q2[ht+0]*INV_2PI, w2ht1 = q2[ht+1]*INV_2PI, w2ht2 = q2[ht+2]*INV_2PI, w2ht3 = q2[ht+3]*INV_2PI;
    const float w3ho0 = q3[ho+0]*INV_2PI, w3ho1 = q3[ho+1]*INV_2PI, w3ho2 = q3[ho+2]*INV_2PI, w3ho3 = q3[ho+3]*INV_2PI;
    const float w3ht0 = q3[ht+0]*INV_2PI, w3ht1 = q3[ht+1]*INV_2PI, w3ht2 = q3[ht+2]*INV_2PI, w3ht3 = q3[ht+3]*INV_2PI;

    const float bs0 = bg[r0 + 0] * INV_2PI;
    const float bs1 = bg[r0 + 1] * INV_2PI;
    const float bs2 = bg[r0 + 2] * INV_2PI;
    const float bs3 = bg[r0 + 3] * INV_2PI;

    // ---- layer-1 trig for own 4 wires ----
    float s10, c10, s11, c11, s12, c12, s13, c13;
    __sincosf(pp[r0 + 0], &s10, &c10);
    __sincosf(pp[r0 + 1], &s11, &c11);
    __sincosf(pp[r0 + 2], &s12, &c12);
    __sincosf(pp[r0 + 3], &s13, &c13);

    // ---- layer-2 coeffs for all 8 wires ----
    float g2_0, g2_1, g2_2, g2_3, g2_4, g2_5, g2_6, g2_7;
    float hn_0, hn_1, hn_2, hn_3, hn_4, hn_5, hn_6, hn_7;
    {
        float s, c;
        __sincosf(pp[HH + 0], &s, &c); g2_0 = c; hn_0 = -s;
        __sincosf(pp[HH + 1], &s, &c); g2_1 = c; hn_1 = -s;
        __sincosf(pp[HH + 2], &s, &c); g2_2 = c; hn_2 = -s;
        __sincosf(pp[HH + 3], &s, &c); g2_3 = c; hn_3 = -s;
        __sincosf(pp[HH + 4], &s, &c); g2_4 = c; hn_4 = -s;
        __sincosf(pp[HH + 5], &s, &c); g2_5 = c; hn_5 = -s;
        __sincosf(pp[HH + 6], &s, &c); g2_6 = c; hn_6 = -s;
        __sincosf(pp[HH + 7], &s, &c); g2_7 = c; hn_7 = -s;
    }

    const float kPre2 = (gate == 2) ? (-2.0f * LOG2E) : (-1.0f * LOG2E);
    const float kPost = (gate == 2) ?  2.0f :  1.0f;
    const float kAdd  = (gate == 2) ? -1.0f :  0.0f;
    const bool g1b = (gate & 1) != 0;
    const bool g2b = (gate & 2) != 0;

    float cs0 = 0.f, cs1 = 0.f, cs2 = 0.f, cs3 = 0.f;
    float h0 = 0.f, h1 = 0.f, h2 = 0.f, h3 = 0.f;
    float rh0 = 0.f, rh1 = 0.f, rh2 = 0.f, rh3 = 0.f;

    const float* xp = inp + (size_t)b * DD;
    const int jj = 4 * part + gate;
    float* op = out + (size_t)b * HH + jj;

    // prefetch x_0
    float4 px0 = *(const float4*)(xp + 0);
    float4 px1 = *(const float4*)(xp + 4);
    float4 px2 = *(const float4*)(xp + 8);
    float4 px3 = *(const float4*)(xp + 12);

    #pragma unroll 8
    for (int t = 0; t < TT; ++t) {
        // ---- matvec x-part for 4 rows (independent of recurrent state) ----
        float ab0, ab1, ab2, ab3;
        MV_X(w0, bs0, ab0);
        MV_X(w1, bs1, ab1);
        MV_X(w2, bs2, ab2);
        MV_X(w3, bs3, ab3);

        // ---- prefetch next x ----
        const float* xn = xp + ((t < TT - 1) ? (size_t)BB * DD : 0);
        px0 = *(const float4*)(xn + 0);
        px1 = *(const float4*)(xn + 4);
        px2 = *(const float4*)(xn + 8);
        px3 = *(const float4*)(xn + 12);
        xp = xn;

        // ---- h-part (own + DPP'd remote) -> angles (revolutions) ----
        float a0, a1, a2, a3;
        MV_H(w0, ab0, a0);
        MV_H(w1, ab1, a1);
        MV_H(w2, ab2, a2);
        MV_H(w3, ab3, a3);

        // ---- trig for own 4 wires + own Bloch comps ----
        float sa0 = __builtin_amdgcn_sinf(a0), ca0 = __builtin_amdgcn_cosf(a0);
        float sa1 = __builtin_amdgcn_sinf(a1), ca1 = __builtin_amdgcn_cosf(a1);
        float sa2 = __builtin_amdgcn_sinf(a2), ca2 = __builtin_amdgcn_cosf(a2);
        float sa3 = __builtin_amdgcn_sinf(a3), ca3 = __builtin_amdgcn_cosf(a3);
        float bxo0 = s10 * ca0, bzo0 = c10 * ca0;
        float bxo1 = s11 * ca1, bzo1 = c11 * ca1;
        float bxo2 = s12 * ca2, bzo2 = c12 * ca2;
        float bxo3 = s13 * ca3, bzo3 = c13 * ca3;

        // ---- part-exchange via DPP row_ror:8 ----
        float rbx0 = DPPX8(bxo0), rbx1 = DPPX8(bxo1), rbx2 = DPPX8(bxo2), rbx3 = DPPX8(bxo3);
        float rsy0 = DPPX8(sa0),  rsy1 = DPPX8(sa1),  rsy2 = DPPX8(sa2),  rsy3 = DPPX8(sa3);
        float rbz0 = DPPX8(bzo0), rbz1 = DPPX8(bzo1), rbz2 = DPPX8(bzo2), rbz3 = DPPX8(bzo3);

        // ---- place into absolute wire order ----
        float bxv0 = part ? rbx0 : bxo0, bxv1 = part ? rbx1 : bxo1;
        float bxv2 = part ? rbx2 : bxo2, bxv3 = part ? rbx3 : bxo3;
        float bxv4 = part ? bxo0 : rbx0, bxv5 = part ? bxo1 : rbx1;
        float bxv6 = part ? bxo2 : rbx2, bxv7 = part ? bxo3 : rbx3;
        float syv0 = part ? rsy0 : sa0,  syv1 = part ? rsy1 : sa1;
        float syv2 = part ? rsy2 : sa2,  syv3 = part ? rsy3 : sa3;
        float syv4 = part ? sa0 : rsy0,  syv5 = part ? sa1 : rsy1;
        float syv6 = part ? sa2 : rsy2,  syv7 = part ? sa3 : rsy3;
        float bzv0 = part ? rbz0 : bzo0, bzv1 = part ? rbz1 : bzo1;
        float bzv2 = part ? rbz2 : bzo2, bzv3 = part ? rbz3 : bzo3;
        float bzv4 = part ? bzo0 : rbz0, bzv5 = part ? bzo1 : rbz1;
        float bzv6 = part ? bzo2 : rbz2, bzv7 = part ? bzo3 : rbz3;

        // ---- bond-2 transfer recursion -> E0..E7 ----
        float E0, E1, E2, E3, E4, E5, E6, E7;
        float f0 = g2_0 * bzv0;
        float fx = hn_0 * bxv0;
        float fy = hn_0 * syv0;
        float fz = g2_0;
        E0 = fmaf(bxv1, fx, f0);
        RSTEP(1, 2); RSTEP(2, 3); RSTEP(3, 4);
        RSTEP(4, 5); RSTEP(5, 6); RSTEP(6, 7);
        {
            float n0_ = g2_7 * fmaf(bzv7, fz, -(syv7 * fy));
            float nx_ = hn_7 * fmaf(bxv7, f0, fx);
            E7 = n0_ + nx_;
        }

        // ---- nonlinearity G for own 4 wires ----
        float e0 = part ? E4 : E0, e1 = part ? E5 : E1;
        float e2 = part ? E6 : E2, e3 = part ? E7 : E3;
        float G0 = fmaf(kPost, fast_rcp(1.0f + __builtin_amdgcn_exp2f(kPre2 * e0)), kAdd);
        float G1 = fmaf(kPost, fast_rcp(1.0f + __builtin_amdgcn_exp2f(kPre2 * e1)), kAdd);
        float G2 = fmaf(kPost, fast_rcp(1.0f + __builtin_amdgcn_exp2f(kPre2 * e2)), kAdd);
        float G3 = fmaf(kPost, fast_rcp(1.0f + __builtin_amdgcn_exp2f(kPre2 * e3)), kAdd);

        // ---- quad exchange + cs updates (keep oj for later) ----
        float o0_, o1_, o2_, o3_;
        {
            float fj = QBCAST(G0, 0), ij = QBCAST(G0, 1), uj = QBCAST(G0, 2); o0_ = QBCAST(G0, 3);
            cs0 = fmaf(fj, cs0, ij * uj);
        }
        {
            float fj = QBCAST(G1, 0), ij = QBCAST(G1, 1), uj = QBCAST(G1, 2); o1_ = QBCAST(G1, 3);
            cs1 = fmaf(fj, cs1, ij * uj);
        }
        {
            float fj = QBCAST(G2, 0), ij = QBCAST(G2, 1), uj = QBCAST(G2, 2); o2_ = QBCAST(G2, 3);
            cs2 = fmaf(fj, cs2, ij * uj);
        }
        {
            float fj = QBCAST(G3, 0), ij = QBCAST(G3, 1), uj = QBCAST(G3, 2); o3_ = QBCAST(G3, 3);
            cs3 = fmaf(fj, cs3, ij * uj);
        }

        // ---- tanh dedup: each quad-lane computes tanh(cs_gate); spread via QBCAST ----
        float sA_ = g1b ? cs1 : cs0;
        float sB_ = g1b ? cs3 : cs2;
        float SEL = g2b ? sB_ : sA_;
        float TH  = fmaf(2.0f, fast_rcp(1.0f + __builtin_amdgcn_exp2f(NEG2LOG2E * SEL)), -1.0f);
        float th0 = QBCAST(TH, 0), th1 = QBCAST(TH, 1), th2 = QBCAST(TH, 2), th3 = QBCAST(TH, 3);
        h0 = o0_ * th0; h1 = o1_ * th1; h2 = o2_ * th2; h3 = o3_ * th3;

        // ---- remote h via DPP (consumed by next step's MV_H) ----
        rh0 = DPPX8(h0); rh1 = DPPX8(h1); rh2 = DPPX8(h2); rh3 = DPPX8(h3);

        // ---- store h_t: lane stores j = 4*part + gate ----
        float sv = (gate == 0) ? h0 : (gate == 1) ? h1 : (gate == 2) ? h2 : h3;
        *op = sv;
        op += (size_t)BB * HH;
    }

    // ---- final hx, cx ----
    const size_t hx_off = (size_t)TT * BB * HH;
    float sv = (gate == 0) ? h0  : (gate == 1) ? h1  : (gate == 2) ? h2  : h3;
    float sA_ = g1b ? cs1 : cs0;
    float sB_ = g1b ? cs3 : cs2;
    float cv  = g2b ? sB_ : sA_;
    out[hx_off + (size_t)b * HH + jj] = sv;
    out[hx_off + (size_t)BB * HH + (size_t)b * HH + jj] = cv;
}

extern "C" void kernel_launch(void* const* d_in, const int* in_sizes, int n_in,
                              void* d_out, int out_size, void* d_ws, size_t ws_size,
                              hipStream_t stream) {
    (void)in_sizes; (void)n_in; (void)d_ws; (void)ws_size; (void)out_size;
    const float* inp = (const float*)d_in[0];
    const float* Wf  = (const float*)d_in[1];
    const float* bf  = (const float*)d_in[2];
    const float* Wi  = (const float*)d_in[3];
    const float* bi  = (const float*)d_in[4];
    const float* Wu  = (const float*)d_in[5];
    const float* bu  = (const float*)d_in[6];
    const float* Wo  = (const float*)d_in[7];
    const float* bo  = (const float*)d_in[8];
    const float* pf  = (const float*)d_in[9];
    const float* pi  = (const float*)d_in[10];
    const float* pu  = (const float*)d_in[11];
    const float* po  = (const float*)d_in[12];
    float* out = (float*)d_out;

    const int threads = BB * 8;    // 8 lanes (4 gates x 2 parts) per sample
    dim3 block(256);
    dim3 grid(threads / 256);
    qlstm_fused_kernel<<<grid, block, 0, stream>>>(inp, Wf, bf, Wi, bi, Wu, bu,
                                                   Wo, bo, pf, pi, pu, po, out);
}

// Round 19
// 153.773 us; speedup vs baseline: 1.0177x; 1.0177x over previous
//
#include <hip/hip_runtime.h>

#define TT 256
#define BB 8192
#define DD 16
#define HH 8

#define INV_2PI 0.15915494309189535f
#define LOG2E   1.4426950408889634f
#define NEG2LOG2E (-2.0f * LOG2E)

__device__ __forceinline__ float fast_rcp(float v) { return __builtin_amdgcn_rcpf(v); }

// part-exchange: lane ^ 8 within a 16-lane row == DPP row_ror:8 (direction-symmetric). No DS.
#define DPPX8(v) __int_as_float(__builtin_amdgcn_mov_dpp(__float_as_int(v), 0x128, 0xF, 0xF, true))
// quad broadcast via DPP quad_perm
#define QBCAST(x, g) __int_as_float(__builtin_amdgcn_mov_dpp(__float_as_int(x), (g)*0x55, 0xF, 0xF, true))

// matvec x-part for one row (flat 16-float weight array W, bias seed BS) -> AB
#define MV_X(W, BS, AB) do { \
    float A_ = fmaf(W[0], px0.x, BS); \
    A_ = fmaf(W[1],  px0.y, A_); A_ = fmaf(W[2],  px0.z, A_); \
    A_ = fmaf(W[3],  px0.w, A_); A_ = fmaf(W[4],  px1.x, A_); \
    A_ = fmaf(W[5],  px1.y, A_); A_ = fmaf(W[6],  px1.z, A_); \
    A_ = fmaf(W[7],  px1.w, A_); \
    float B_ = W[8] * px2.x; \
    B_ = fmaf(W[9],  px2.y, B_); B_ = fmaf(W[10], px2.z, B_); \
    B_ = fmaf(W[11], px2.w, B_); B_ = fmaf(W[12], px3.x, B_); \
    B_ = fmaf(W[13], px3.y, B_); B_ = fmaf(W[14], px3.z, B_); \
    B_ = fmaf(W[15], px3.w, B_); \
    AB = A_ + B_; } while (0)

// matvec h-part: own-part h (local regs) + remote-part h (DPP'd), weights pre-split at setup
#define MV_H(P, AB, A) do { \
    float C_ = P##ho0 * h0; \
    C_ = fmaf(P##ho1, h1, C_); C_ = fmaf(P##ho2, h2, C_); C_ = fmaf(P##ho3, h3, C_); \
    float D_ = P##ht0 * rh0; \
    D_ = fmaf(P##ht1, rh1, D_); D_ = fmaf(P##ht2, rh2, D_); D_ = fmaf(P##ht3, rh3, D_); \
    A = (AB + C_) + D_; } while (0)

// one transfer-recursion step at wire i
#define RSTEP(i, inext) do { \
    float n0_ = g2_##i * fmaf(bzv##i, fz, -(syv##i * fy)); \
    float nx_ = hn_##i * fmaf(bxv##i, f0, fx); \
    float ny_ = hn_##i * fmaf(syv##i, fz, bzv##i * fy); \
    float nz_ = g2_##i * fmaf(bxv##i, fx, f0); \
    f0 = n0_; fx = nx_; fy = ny_; fz = nz_; \
    E##i = fmaf(bxv##inext, fx, f0); } while (0)

__global__ __launch_bounds__(256, 1)
void qlstm_fused_kernel(const float* __restrict__ inp,
                        const float* __restrict__ Wf, const float* __restrict__ bfv,
                        const float* __restrict__ Wi, const float* __restrict__ biv,
                        const float* __restrict__ Wu, const float* __restrict__ buv,
                        const float* __restrict__ Wo, const float* __restrict__ bov,
                        const float* __restrict__ pf, const float* __restrict__ pi,
                        const float* __restrict__ pu, const float* __restrict__ po,
                        float* __restrict__ out)
{
    const int tid  = blockIdx.x * blockDim.x + threadIdx.x;
    const int gate = tid & 3;          // lane bits 0-1: gate (quad)
    const int samp = (tid >> 2) & 1;   // lane bit 2: which of the row's 2 samples
    const int part = (tid >> 3) & 1;   // lane bit 3: part; xor-8 = row_ror:8
    const int b    = ((tid >> 4) << 1) | samp;   // sample index

    const float* Wg = (gate == 0) ? Wf  : (gate == 1) ? Wi  : (gate == 2) ? Wu  : Wo;
    const float* bg = (gate == 0) ? bfv : (gate == 1) ? biv : (gate == 2) ? buv : bov;
    const float* pp = (gate == 0) ? pf  : (gate == 1) ? pi  : (gate == 2) ? pu  : po;

    // ---- own 4 weight rows: x-part flat; h-part split own/remote (named scalars) ----
    const int r0 = 4 * part;
    float w0[16], w1[16], w2[16], w3[16];
    {
        const float* p0 = Wg + (r0 + 0) * 24;
        const float* p1 = Wg + (r0 + 1) * 24;
        const float* p2 = Wg + (r0 + 2) * 24;
        const float* p3 = Wg + (r0 + 3) * 24;
        #pragma unroll
        for (int k = 0; k < 4; ++k) {
            float4 v0 = *(const float4*)(p0 + 4 * k);
            float4 v1 = *(const float4*)(p1 + 4 * k);
            float4 v2 = *(const float4*)(p2 + 4 * k);
            float4 v3 = *(const float4*)(p3 + 4 * k);
            w0[4*k+0] = v0.x * INV_2PI; w0[4*k+1] = v0.y * INV_2PI;
            w0[4*k+2] = v0.z * INV_2PI; w0[4*k+3] = v0.w * INV_2PI;
            w1[4*k+0] = v1.x * INV_2PI; w1[4*k+1] = v1.y * INV_2PI;
            w1[4*k+2] = v1.z * INV_2PI; w1[4*k+3] = v1.w * INV_2PI;
            w2[4*k+0] = v2.x * INV_2PI; w2[4*k+1] = v2.y * INV_2PI;
            w2[4*k+2] = v2.z * INV_2PI; w2[4*k+3] = v2.w * INV_2PI;
            w3[4*k+0] = v3.x * INV_2PI; w3[4*k+1] = v3.y * INV_2PI;
            w3[4*k+2] = v3.z * INV_2PI; w3[4*k+3] = v3.w * INV_2PI;
        }
    }
    const int ho = 16 + 4 * part, ht = 16 + 4 * (1 - part);
    const float* q0 = Wg + (r0 + 0) * 24;
    const float* q1 = Wg + (r0 + 1) * 24;
    const float* q2 = Wg + (r0 + 2) * 24;
    const float* q3 = Wg + (r0 + 3) * 24;
    const float w0ho0 = q0[ho+0]*INV_2PI, w0ho1 = q0[ho+1]*INV_2PI, w0ho2 = q0[ho+2]*INV_2PI, w0ho3 = q0[ho+3]*INV_2PI;
    const float w0ht0 = q0[ht+0]*INV_2PI, w0ht1 = q0[ht+1]*INV_2PI, w0ht2 = q0[ht+2]*INV_2PI, w0ht3 = q0[ht+3]*INV_2PI;
    const float w1ho0 = q1[ho+0]*INV_2PI, w1ho1 = q1[ho+1]*INV_2PI, w1ho2 = q1[ho+2]*INV_2PI, w1ho3 = q1[ho+3]*INV_2PI;
    const float w1ht0 = q1[ht+0]*INV_2PI, w1ht1 = q1[ht+1]*INV_2PI, w1ht2 = q1[ht+2]*INV_2PI, w1ht3 = q1[ht+3]*INV_2PI;
    const float w2ho0 = q2[ho+0]*INV_2PI, w2ho1 = q2[ho+1]*INV_2PI, w2ho2 = q2[ho+2]*INV_2PI, w2ho3 = q2[ho+3]*INV_2PI;
    const float w2ht0 = q2[ht+0]*INV_2PI, w2ht1 = q2[ht+1]*INV_2PI, w2ht2 = q2[ht+2]*INV_2PI, w2ht3 = q2[ht+3]*INV_2PI;
    const float w3ho0 = q3[ho+0]*INV_2PI, w3ho1 = q3[ho+1]*INV_2PI, w3ho2 = q3[ho+2]*INV_2PI, w3ho3 = q3[ho+3]*INV_2PI;
    const float w3ht0 = q3[ht+0]*INV_2PI, w3ht1 = q3[ht+1]*INV_2PI, w3ht2 = q3[ht+2]*INV_2PI, w3ht3 = q3[ht+3]*INV_2PI;

    const float bs0 = bg[r0 + 0] * INV_2PI;
    const float bs1 = bg[r0 + 1] * INV_2PI;
    const float bs2 = bg[r0 + 2] * INV_2PI;
    const float bs3 = bg[r0 + 3] * INV_2PI;

    // ---- layer-1 trig for own 4 wires ----
    float s10, c10, s11, c11, s12, c12, s13, c13;
    __sincosf(pp[r0 + 0], &s10, &c10);
    __sincosf(pp[r0 + 1], &s11, &c11);
    __sincosf(pp[r0 + 2], &s12, &c12);
    __sincosf(pp[r0 + 3], &s13, &c13);

    // ---- layer-2 coeffs for all 8 wires ----
    float g2_0, g2_1, g2_2, g2_3, g2_4, g2_5, g2_6, g2_7;
    float hn_0, hn_1, hn_2, hn_3, hn_4, hn_5, hn_6, hn_7;
    {
        float s, c;
        __sincosf(pp[HH + 0], &s, &c); g2_0 = c; hn_0 = -s;
        __sincosf(pp[HH + 1], &s, &c); g2_1 = c; hn_1 = -s;
        __sincosf(pp[HH + 2], &s, &c); g2_2 = c; hn_2 = -s;
        __sincosf(pp[HH + 3], &s, &c); g2_3 = c; hn_3 = -s;
        __sincosf(pp[HH + 4], &s, &c); g2_4 = c; hn_4 = -s;
        __sincosf(pp[HH + 5], &s, &c); g2_5 = c; hn_5 = -s;
        __sincosf(pp[HH + 6], &s, &c); g2_6 = c; hn_6 = -s;
        __sincosf(pp[HH + 7], &s, &c); g2_7 = c; hn_7 = -s;
    }

    const float kPre2 = (gate == 2) ? (-2.0f * LOG2E) : (-1.0f * LOG2E);
    const float kPost = (gate == 2) ?  2.0f :  1.0f;
    const float kAdd  = (gate == 2) ? -1.0f :  0.0f;
    const bool g1b = (gate & 1) != 0;
    const bool g2b = (gate & 2) != 0;

    float cs0 = 0.f, cs1 = 0.f, cs2 = 0.f, cs3 = 0.f;
    float h0 = 0.f, h1 = 0.f, h2 = 0.f, h3 = 0.f;
    float rh0 = 0.f, rh1 = 0.f, rh2 = 0.f, rh3 = 0.f;

    const float* xp = inp + (size_t)b * DD;
    const int jj = 4 * part + gate;
    float* op = out + (size_t)b * HH + jj;

    // prefetch x_0
    float4 px0 = *(const float4*)(xp + 0);
    float4 px1 = *(const float4*)(xp + 4);
    float4 px2 = *(const float4*)(xp + 8);
    float4 px3 = *(const float4*)(xp + 12);

    #pragma unroll 4
    for (int t = 0; t < TT; ++t) {
        // ---- matvec x-part for 4 rows (independent of recurrent state) ----
        float ab0, ab1, ab2, ab3;
        MV_X(w0, bs0, ab0);
        MV_X(w1, bs1, ab1);
        MV_X(w2, bs2, ab2);
        MV_X(w3, bs3, ab3);

        // ---- prefetch next x ----
        const float* xn = xp + ((t < TT - 1) ? (size_t)BB * DD : 0);
        px0 = *(const float4*)(xn + 0);
        px1 = *(const float4*)(xn + 4);
        px2 = *(const float4*)(xn + 8);
        px3 = *(const float4*)(xn + 12);
        xp = xn;

        // ---- h-part (own + DPP'd remote) -> angles (revolutions) ----
        float a0, a1, a2, a3;
        MV_H(w0, ab0, a0);
        MV_H(w1, ab1, a1);
        MV_H(w2, ab2, a2);
        MV_H(w3, ab3, a3);

        // ---- trig for own 4 wires + own Bloch comps ----
        float sa0 = __builtin_amdgcn_sinf(a0), ca0 = __builtin_amdgcn_cosf(a0);
        float sa1 = __builtin_amdgcn_sinf(a1), ca1 = __builtin_amdgcn_cosf(a1);
        float sa2 = __builtin_amdgcn_sinf(a2), ca2 = __builtin_amdgcn_cosf(a2);
        float sa3 = __builtin_amdgcn_sinf(a3), ca3 = __builtin_amdgcn_cosf(a3);
        float bxo0 = s10 * ca0, bzo0 = c10 * ca0;
        float bxo1 = s11 * ca1, bzo1 = c11 * ca1;
        float bxo2 = s12 * ca2, bzo2 = c12 * ca2;
        float bxo3 = s13 * ca3, bzo3 = c13 * ca3;

        // ---- part-exchange via DPP row_ror:8 ----
        float rbx0 = DPPX8(bxo0), rbx1 = DPPX8(bxo1), rbx2 = DPPX8(bxo2), rbx3 = DPPX8(bxo3);
        float rsy0 = DPPX8(sa0),  rsy1 = DPPX8(sa1),  rsy2 = DPPX8(sa2),  rsy3 = DPPX8(sa3);
        float rbz0 = DPPX8(bzo0), rbz1 = DPPX8(bzo1), rbz2 = DPPX8(bzo2), rbz3 = DPPX8(bzo3);

        // ---- place into absolute wire order ----
        float bxv0 = part ? rbx0 : bxo0, bxv1 = part ? rbx1 : bxo1;
        float bxv2 = part ? rbx2 : bxo2, bxv3 = part ? rbx3 : bxo3;
        float bxv4 = part ? bxo0 : rbx0, bxv5 = part ? bxo1 : rbx1;
        float bxv6 = part ? bxo2 : rbx2, bxv7 = part ? bxo3 : rbx3;
        float syv0 = part ? rsy0 : sa0,  syv1 = part ? rsy1 : sa1;
        float syv2 = part ? rsy2 : sa2,  syv3 = part ? rsy3 : sa3;
        float syv4 = part ? sa0 : rsy0,  syv5 = part ? sa1 : rsy1;
        float syv6 = part ? sa2 : rsy2,  syv7 = part ? sa3 : rsy3;
        float bzv0 = part ? rbz0 : bzo0, bzv1 = part ? rbz1 : bzo1;
        float bzv2 = part ? rbz2 : bzo2, bzv3 = part ? rbz3 : bzo3;
        float bzv4 = part ? bzo0 : rbz0, bzv5 = part ? bzo1 : rbz1;
        float bzv6 = part ? bzo2 : rbz2, bzv7 = part ? bzo3 : rbz3;

        // ---- bond-2 transfer recursion -> E0..E7 ----
        float E0, E1, E2, E3, E4, E5, E6, E7;
        float f0 = g2_0 * bzv0;
        float fx = hn_0 * bxv0;
        float fy = hn_0 * syv0;
        float fz = g2_0;
        E0 = fmaf(bxv1, fx, f0);
        RSTEP(1, 2); RSTEP(2, 3); RSTEP(3, 4);
        RSTEP(4, 5); RSTEP(5, 6); RSTEP(6, 7);
        {
            float n0_ = g2_7 * fmaf(bzv7, fz, -(syv7 * fy));
            float nx_ = hn_7 * fmaf(bxv7, f0, fx);
            E7 = n0_ + nx_;
        }

        // ---- nonlinearity G for own 4 wires ----
        float e0 = part ? E4 : E0, e1 = part ? E5 : E1;
        float e2 = part ? E6 : E2, e3 = part ? E7 : E3;
        float G0 = fmaf(kPost, fast_rcp(1.0f + __builtin_amdgcn_exp2f(kPre2 * e0)), kAdd);
        float G1 = fmaf(kPost, fast_rcp(1.0f + __builtin_amdgcn_exp2f(kPre2 * e1)), kAdd);
        float G2 = fmaf(kPost, fast_rcp(1.0f + __builtin_amdgcn_exp2f(kPre2 * e2)), kAdd);
        float G3 = fmaf(kPost, fast_rcp(1.0f + __builtin_amdgcn_exp2f(kPre2 * e3)), kAdd);

        // ---- quad exchange + cs updates (keep oj for later) ----
        float o0_, o1_, o2_, o3_;
        {
            float fj = QBCAST(G0, 0), ij = QBCAST(G0, 1), uj = QBCAST(G0, 2); o0_ = QBCAST(G0, 3);
            cs0 = fmaf(fj, cs0, ij * uj);
        }
        {
            float fj = QBCAST(G1, 0), ij = QBCAST(G1, 1), uj = QBCAST(G1, 2); o1_ = QBCAST(G1, 3);
            cs1 = fmaf(fj, cs1, ij * uj);
        }
        {
            float fj = QBCAST(G2, 0), ij = QBCAST(G2, 1), uj = QBCAST(G2, 2); o2_ = QBCAST(G2, 3);
            cs2 = fmaf(fj, cs2, ij * uj);
        }
        {
            float fj = QBCAST(G3, 0), ij = QBCAST(G3, 1), uj = QBCAST(G3, 2); o3_ = QBCAST(G3, 3);
            cs3 = fmaf(fj, cs3, ij * uj);
        }

        // ---- tanh dedup: each quad-lane computes tanh(cs_gate); spread via QBCAST ----
        float sA_ = g1b ? cs1 : cs0;
        float sB_ = g1b ? cs3 : cs2;
        float SEL = g2b ? sB_ : sA_;
        float TH  = fmaf(2.0f, fast_rcp(1.0f + __builtin_amdgcn_exp2f(NEG2LOG2E * SEL)), -1.0f);
        float th0 = QBCAST(TH, 0), th1 = QBCAST(TH, 1), th2 = QBCAST(TH, 2), th3 = QBCAST(TH, 3);
        h0 = o0_ * th0; h1 = o1_ * th1; h2 = o2_ * th2; h3 = o3_ * th3;

        // ---- remote h via DPP (consumed by next step's MV_H) ----
        rh0 = DPPX8(h0); rh1 = DPPX8(h1); rh2 = DPPX8(h2); rh3 = DPPX8(h3);

        // ---- store h_t: lane stores j = 4*part + gate ----
        float sv = (gate == 0) ? h0 : (gate == 1) ? h1 : (gate == 2) ? h2 : h3;
        *op = sv;
        op += (size_t)BB * HH;
    }

    // ---- final hx, cx ----
    const size_t hx_off = (size_t)TT * BB * HH;
    float sv = (gate == 0) ? h0  : (gate == 1) ? h1  : (gate == 2) ? h2  : h3;
    float sA_ = g1b ? cs1 : cs0;
    float sB_ = g1b ? cs3 : cs2;
    float cv  = g2b ? sB_ : sA_;
    out[hx_off + (size_t)b * HH + jj] = sv;
    out[hx_off + (size_t)BB * HH + (size_t)b * HH + jj] = cv;
}

extern "C" void kernel_launch(void* const* d_in, const int* in_sizes, int n_in,
                              void* d_out, int out_size, void* d_ws, size_t ws_size,
                              hipStream_t stream) {
    (void)in_sizes; (void)n_in; (void)d_ws; (void)ws_size; (void)out_size;
    const float* inp = (const float*)d_in[0];
    const float* Wf  = (const float*)d_in[1];
    const float* bf  = (const float*)d_in[2];
    const float* Wi  = (const float*)d_in[3];
    const float* bi  = (const float*)d_in[4];
    const float* Wu  = (const float*)d_in[5];
    const float* bu  = (const float*)d_in[6];
    const float* Wo  = (const float*)d_in[7];
    const float* bo  = (const float*)d_in[8];
    const float* pf  = (const float*)d_in[9];
    const float* pi  = (const float*)d_in[10];
    const float* pu  = (const float*)d_in[11];
    const float* po  = (const float*)d_in[12];
    float* out = (float*)d_out;

    const int threads = BB * 8;    // 8 lanes (4 gates x 2 parts) per sample
    dim3 block(256);
    dim3 grid(threads / 256);
    qlstm_fused_kernel<<<grid, block, 0, stream>>>(inp, Wf, bf, Wi, bi, Wu, bu,
                                                   Wo, bo, pf, pi, pu, po, out);
}